// Round 9
// baseline (680.310 us; speedup 1.0000x reference)
//
#include <hip/hip_runtime.h>
#include <hip/hip_bf16.h>
#include <math.h>

#define CIN 256
#define NUM_CLASSES 91
#define NUM_ANCH 9
#define KEY_CAP 65536
#define NCAND 5000
#define BBOX_CLIP_F 4.135166556742356f
#define CLS_THRESH 0.05f
#define PITCH 5456
#define PP_TOT 5972
#define PLANE_E 1528832      // ushorts per plane (8*5972*32)
#define PLANE_B 3057664      // bytes per plane
#define ABUF_B  6115328      // bytes per act buffer (hi+lo plane)
#define SLB     147456       // bytes per 16-cout weight-frag slice
#define LO_OFF  13312        // LDS offset of lo plane within a phase
#define PHASE   26624        // LDS bytes per phase (hi+lo)

typedef __attribute__((ext_vector_type(4))) float f4;
typedef _Float16 h8 __attribute__((ext_vector_type(8)));

#define MFMA(a,b,c) __builtin_amdgcn_mfma_f32_16x16x32_f16(a,b,c,0,0,0)

__constant__ int c_wsh[5]  = {6,5,4,3,2};
__constant__ int c_hw[5]   = {4096,1024,256,64,16};
__constant__ int c_wp[5]   = {66,34,18,10,6};
__constant__ int c_poff[5] = {0,4356,5512,5836,5936};
__constant__ int c_slen[5] = {198,136,108,100,36};   // strip len for 64-px tiles
__constant__ int c_loff[5] = {0,4096,5120,5376,5440};
__constant__ int c_aoff[5] = {0,36864,46080,48384,48960};
// wf slice ranges: clsL2,clsL3,clsL4,regL1,regL2,regL3,regL4,clsHead(52),regHead(4),clsL1(16)
__constant__ int s_cum[11] = {0,16,32,48,64,80,96,112,164,168,184};

__device__ __forceinline__ unsigned short f16r(float f) {
    _Float16 h = (_Float16)f;
    return __builtin_bit_cast(unsigned short, h);
}
__device__ __forceinline__ float f16tof(unsigned short u) {
    return (float)__builtin_bit_cast(_Float16, u);
}
// split v = h + l/4096, h zero-guarded against f16 denormal flush, l pre-scaled x4096
__device__ __forceinline__ void split16(float v, unsigned short& h, unsigned short& l) {
    unsigned short hh = (fabsf(v) < 6.103515625e-05f) ? (unsigned short)0 : f16r(v);
    h = hh;
    l = f16r((v - f16tof(hh)) * 4096.0f);
}
__device__ __forceinline__ void gl_lds(const void* g, void* l) {
    __builtin_amdgcn_global_load_lds((const __attribute__((address_space(1))) void*)g,
                                     (__attribute__((address_space(3))) void*)l, 16, 0, 0);
}
__device__ __forceinline__ void tile_geom(int tile, int& lvl, int& px0, int& y0) {
    if (tile < 64)      { lvl = 0; px0 = tile << 6; y0 = tile; }
    else if (tile < 80) { lvl = 1; int j = tile - 64; px0 = j << 6; y0 = j << 1; }
    else if (tile < 84) { lvl = 2; int j = tile - 80; px0 = j << 6; y0 = j << 2; }
    else if (tile == 84){ lvl = 3; px0 = 0; y0 = 0; }
    else                { lvl = 4; px0 = 0; y0 = 0; }
}
// swizzled within-pixel slot for cout/cin group: slot = quad ^ (abs_ppix & 3)

// ---------------- pad + split + chunk the input pyramid ----------------
__global__ void pad_k(const float* __restrict__ f0, const float* __restrict__ f1,
                      const float* __restrict__ f2, const float* __restrict__ f3,
                      const float* __restrict__ f4, unsigned short* __restrict__ IN) {
    int gid = blockIdx.x * 256 + threadIdx.x;
    if (gid >= 256 * PITCH) return;
    int cin = gid / PITCH, g = gid - cin * PITCH;
    int lvl = (g < 4096) ? 0 : (g < 5120) ? 1 : (g < 5376) ? 2 : (g < 5440) ? 3 : 4;
    const float* f = (lvl == 0) ? f0 : (lvl == 1) ? f1 : (lvl == 2) ? f2 : (lvl == 3) ? f3 : f4;
    int pix = g - c_loff[lvl];
    int wsh = c_wsh[lvl];
    int y = pix >> wsh, x = pix & ((1 << wsh) - 1);
    float v = f[(size_t)cin * c_hw[lvl] + pix];
    unsigned short h, l;
    split16(v, h, l);
    size_t ppix = c_poff[lvl] + (size_t)(y + 1) * c_wp[lvl] + x + 1;
    int qc = (cin >> 3) & 3;
    size_t idx = ((size_t)(cin >> 5) * PP_TOT + ppix) * 32 +
                 (size_t)((qc ^ ((int)ppix & 3)) << 3) + (cin & 7);
    IN[idx] = h;
    IN[PLANE_E + idx] = l;
}

// ---------------- weight fragment prep (f16 hi + scaled-lo, MFMA B-frag order) ----------------
__global__ void wprep_k(const float* __restrict__ ctw, const float* __restrict__ rtw,
                        const float* __restrict__ cow, const float* __restrict__ row_,
                        unsigned short* __restrict__ wf) {
    int gid = blockIdx.x * 256 + threadIdx.x;
    if (gid >= 184 * 72 * 64) return;
    int lane = gid & 63;
    int t = gid >> 6;
    int tap = t % 9;
    int t2 = t / 9;
    int chunk = t2 & 7;
    int cbg = t2 >> 3;
    int r = 0;
#pragma unroll
    for (int i = 1; i <= 10; ++i) if (cbg >= s_cum[i]) r = i;
    int cbl = cbg - s_cum[r];
    const float* src;
    int coutCnt;
    if (r < 3)       { src = ctw + (size_t)(r + 1) * 589824; coutCnt = 256; }
    else if (r < 7)  { src = rtw + (size_t)(r - 3) * 589824; coutCnt = 256; }
    else if (r == 7) { src = cow; coutCnt = 819; }
    else if (r == 8) { src = row_; coutCnt = 36; }
    else             { src = ctw; coutCnt = 256; }
    int cout = cbl * 16 + (lane & 15);
    int q = lane >> 4;
    unsigned short H[8], L[8];
#pragma unroll
    for (int j = 0; j < 8; ++j) {
        int cin = chunk * 32 + q * 8 + j;
        float v = (cout < coutCnt) ? src[((size_t)cout * 256 + cin) * 9 + tap] : 0.0f;
        split16(v, H[j], L[j]);
    }
    size_t off = (size_t)cbg * 73728 + (size_t)(chunk * 9 + tap) * 1024 + (size_t)lane * 8;
#pragma unroll
    for (int j = 0; j < 8; ++j) { wf[off + j] = H[j]; wf[off + 512 + j] = L[j]; }
}

// ---------------- MFMA K-loop: wave = 32px x 64cout, dbuf LDS, B register-pipelined ----------------
__device__ __forceinline__ void kloop(const unsigned short* __restrict__ src,
        const char* __restrict__ wf0, char* sm, int wid, int lane, int quad,
        int s_base, int s_len, int Wp, const int relrow[2], f4 acc1[2][4], f4 acc2[2][4]) {
    const char* wp = wf0 + lane * 16;
    int nc = (s_len * 64 + 1023) >> 10;
    const char* gbase = (const char*)src;
    {
        const char* g = gbase + (size_t)s_base * 64;
        for (int c = wid; c < nc; c += 2) {
            gl_lds(g + (size_t)c * 1024 + (size_t)lane * 16, sm + c * 1024);
            gl_lds(g + PLANE_B + (size_t)c * 1024 + (size_t)lane * 16, sm + LO_OFF + c * 1024);
        }
    }
    h8 bh[4], bl[4];
#pragma unroll
    for (int sl = 0; sl < 4; ++sl) {
        bh[sl] = *(const h8*)(wp + (size_t)sl * SLB);
        bl[sl] = *(const h8*)(wp + (size_t)sl * SLB + 1024);
    }
    __syncthreads();
    int qsh = quad << 4;
    for (int chunk = 0; chunk < 8; ++chunk) {
        char* smc = sm + (chunk & 1) * PHASE;
        if (chunk < 7) {   // issue next-chunk staging BEFORE compute
            char* smn = sm + ((chunk & 1) ^ 1) * PHASE;
            const char* g = gbase + ((size_t)(chunk + 1) * PP_TOT + s_base) * 64;
            for (int c = wid; c < nc; c += 2) {
                gl_lds(g + (size_t)c * 1024 + (size_t)lane * 16, smn + c * 1024);
                gl_lds(g + PLANE_B + (size_t)c * 1024 + (size_t)lane * 16, smn + LO_OFF + c * 1024);
            }
        }
#pragma unroll
        for (int tap = 0; tap < 9; ++tap) {
            int kt = chunk * 9 + tap;
            int wo2 = ((kt < 71) ? kt + 1 : kt) * 2048;   // next-tap B prefetch (clamped)
            h8 nh[4], nl[4];
#pragma unroll
            for (int sl = 0; sl < 4; ++sl) {
                nh[sl] = *(const h8*)(wp + (size_t)sl * SLB + wo2);
                nl[sl] = *(const h8*)(wp + (size_t)sl * SLB + wo2 + 1024);
            }
            int toff = ((tap / 3) - 1) * Wp + (tap % 3) - 1;
            h8 ah[2], al[2];
#pragma unroll
            for (int mb = 0; mb < 2; ++mb) {
                int arow = relrow[mb] + toff;                       // row within strip
                int sw = qsh ^ (((s_base + arow) & 3) << 4);        // swizzled 16B slot
                int addr = arow * 64 + sw;
                ah[mb] = *(const h8*)(smc + addr);
                al[mb] = *(const h8*)(smc + LO_OFF + addr);
            }
#pragma unroll
            for (int sl = 0; sl < 4; ++sl) {
                acc1[0][sl] = MFMA(ah[0], bh[sl], acc1[0][sl]);
                acc2[0][sl] = MFMA(al[0], bh[sl], acc2[0][sl]);
                acc2[0][sl] = MFMA(ah[0], bl[sl], acc2[0][sl]);
                acc1[1][sl] = MFMA(ah[1], bh[sl], acc1[1][sl]);
                acc2[1][sl] = MFMA(al[1], bh[sl], acc2[1][sl]);
                acc2[1][sl] = MFMA(ah[1], bl[sl], acc2[1][sl]);
            }
#pragma unroll
            for (int sl = 0; sl < 4; ++sl) { bh[sl] = nh[sl]; bl[sl] = nl[sl]; }
        }
        __syncthreads();
    }
}

// ---------------- fused tower layer: 64px x 64cout blocks (2 waves of 32px x 64cout) ----------------
__global__ __launch_bounds__(128, 2) void conv_t(
        const unsigned short* __restrict__ srcC, const unsigned short* __restrict__ srcR,
        unsigned short* __restrict__ dstC, unsigned short* __restrict__ dstR,
        const unsigned short* __restrict__ wfC, const unsigned short* __restrict__ wfR,
        const float* __restrict__ bC, const float* __restrict__ bR) {
    __shared__ __align__(16) char sm[2 * PHASE];
    int tid = threadIdx.x, lane = tid & 63, wid = tid >> 6;
    int quad = lane >> 4, l16 = lane & 15;
    int bx = blockIdx.x;
    int cb = bx & 3, tower = (bx >> 2) & 1, tile = bx >> 3;
    const unsigned short* src = tower ? srcR : srcC;
    unsigned short* dst = tower ? dstR : dstC;
    const unsigned short* wfx = tower ? wfR : wfC;
    const float* bias = tower ? bR : bC;

    int lvl, px0, y0;
    tile_geom(tile, lvl, px0, y0);
    int wsh = c_wsh[lvl], HW = c_hw[lvl], Wp = c_wp[lvl];
    int poff = c_poff[lvl];
    int s_base = poff + y0 * Wp, s_len = c_slen[lvl];
    int Mh = wid * 32;                             // wave: 32 px x 64 couts

    int relrow[2];
#pragma unroll
    for (int mb = 0; mb < 2; ++mb) {
        int p = px0 + Mh + mb * 16 + l16;
        if (p >= HW) p = HW - 1;
        int y = p >> wsh, x = p & ((1 << wsh) - 1);
        relrow[mb] = (y - y0 + 1) * Wp + x + 1;
    }
    f4 acc1[2][4], acc2[2][4];
#pragma unroll
    for (int mb = 0; mb < 2; ++mb)
#pragma unroll
        for (int sl = 0; sl < 4; ++sl) { acc1[mb][sl] = (f4)0.0f; acc2[mb][sl] = (f4)0.0f; }

    const char* wf0 = (const char*)wfx + (size_t)(cb * 4) * SLB;
    kloop(src, wf0, sm, wid, lane, quad, s_base, s_len, Wp, relrow, acc1, acc2);

    int cbase = cb * 64;
    float bv[4];
#pragma unroll
    for (int sl = 0; sl < 4; ++sl) bv[sl] = bias[cbase + sl * 16 + l16];
#pragma unroll
    for (int mb = 0; mb < 2; ++mb) {
        int pb = px0 + Mh + mb * 16 + quad * 4;
#pragma unroll
        for (int r = 0; r < 4; ++r) {
            int p = pb + r;
            bool valid = p < HW;
            int pc = valid ? p : 0;
            int y = pc >> wsh, x = pc & ((1 << wsh) - 1);
            size_t ppix = poff + (size_t)(y + 1) * Wp + x + 1;
#pragma unroll
            for (int sl = 0; sl < 4; ++sl) {
                int coutg = cbase + sl * 16 + l16;
                float v = fmaf(acc2[mb][sl][r], 0.000244140625f, acc1[mb][sl][r]) + bv[sl];
                v = fmaxf(v, 0.0f);
                unsigned short h, l;
                split16(v, h, l);
                int c31 = coutg & 31;
                size_t idx = ((size_t)(coutg >> 5) * PP_TOT + ppix) * 32 +
                             (size_t)(((c31 >> 3) ^ ((int)ppix & 3)) << 3) + (c31 & 7);
                if (valid) { dst[idx] = h; dst[PLANE_E + idx] = l; }
            }
        }
    }
}

// ---------------- fused heads: cls (sigmoid+collect fused) + reg ----------------
__global__ __launch_bounds__(128, 2) void mhead_t(
        const unsigned short* __restrict__ srcC, const unsigned short* __restrict__ srcR,
        const unsigned short* __restrict__ wfCls, const unsigned short* __restrict__ wfReg,
        const float* __restrict__ cob, const float* __restrict__ rob,
        unsigned long long* __restrict__ keys, int* __restrict__ cnt,
        float* __restrict__ regout) {
    __shared__ __align__(16) char sm[2 * PHASE];
    int tid = threadIdx.x, lane = tid & 63, wid = tid >> 6;
    int quad = lane >> 4, l16 = lane & 15;
    int bx = blockIdx.x, tile = bx / 14, sub = bx - tile * 14;
    bool isCls = sub < 13;

    int lvl, px0, y0;
    tile_geom(tile, lvl, px0, y0);
    int wsh = c_wsh[lvl], HW = c_hw[lvl], Wp = c_wp[lvl];
    int poff = c_poff[lvl];
    int s_base = poff + y0 * Wp, s_len = c_slen[lvl];
    int Mh = wid * 32;                             // wave: 32 px x 64 couts

    int relrow[2];
#pragma unroll
    for (int mb = 0; mb < 2; ++mb) {
        int p = px0 + Mh + mb * 16 + l16;
        if (p >= HW) p = HW - 1;
        int y = p >> wsh, x = p & ((1 << wsh) - 1);
        relrow[mb] = (y - y0 + 1) * Wp + x + 1;
    }
    f4 acc1[2][4], acc2[2][4];
#pragma unroll
    for (int mb = 0; mb < 2; ++mb)
#pragma unroll
        for (int sl = 0; sl < 4; ++sl) { acc1[mb][sl] = (f4)0.0f; acc2[mb][sl] = (f4)0.0f; }

    const unsigned short* src = isCls ? srcC : srcR;
    // cls: sub s covers couts [s*64, s*64+64) over 52 slices (tail zero-padded in wf)
    // reg: couts [0,64), real 36, rest zero-padded in wf
    const char* wf0 = isCls ? (const char*)wfCls + (size_t)(sub * 4) * SLB
                            : (const char*)wfReg;
    kloop(src, wf0, sm, wid, lane, quad, s_base, s_len, Wp, relrow, acc1, acc2);

    if (isCls) {
        int chb = sub * 64;
        float cbv[4];
#pragma unroll
        for (int sl = 0; sl < 4; ++sl) {
            int ch = chb + sl * 16 + l16;
            cbv[sl] = (ch < 819) ? cob[ch] : 0.0f;
        }
#pragma unroll
        for (int mb = 0; mb < 2; ++mb) {
            int pb = px0 + Mh + mb * 16 + quad * 4;
#pragma unroll
            for (int r = 0; r < 4; ++r) {
                int p = pb + r;
                bool valid = p < HW;
#pragma unroll
                for (int sl = 0; sl < 4; ++sl) {
                    int ch = chb + sl * 16 + l16;
                    if (valid && ch < 819) {
                        float lg = fmaf(acc2[mb][sl][r], 0.000244140625f, acc1[mb][sl][r]) + cbv[sl];
                        float s = 1.0f / (1.0f + expf(-lg));
                        if (s > CLS_THRESH) {
                            int a = ch / NUM_CLASSES;
                            int cls = ch - a * NUM_CLASSES;
                            unsigned flat = (unsigned)((p * NUM_ANCH + a) * NUM_CLASSES + cls);
                            int pos = atomicAdd(cnt + lvl, 1);
                            if (pos < KEY_CAP)
                                keys[(size_t)lvl * KEY_CAP + pos] =
                                    ((unsigned long long)__float_as_uint(s) << 32) |
                                    (unsigned long long)(~flat);
                        }
                    }
                }
            }
        }
    } else {
        float rbv[4];
#pragma unroll
        for (int sl = 0; sl < 4; ++sl) {
            int ch = sl * 16 + l16;
            rbv[sl] = (ch < 36) ? rob[ch] : 0.0f;
        }
        int loff = c_loff[lvl];
#pragma unroll
        for (int mb = 0; mb < 2; ++mb) {
            int pb = px0 + Mh + mb * 16 + quad * 4;
#pragma unroll
            for (int r = 0; r < 4; ++r) {
                int p = pb + r;
                bool valid = p < HW;
#pragma unroll
                for (int sl = 0; sl < 4; ++sl) {
                    int ch = sl * 16 + l16;
                    if (valid && ch < 36)
                        regout[(size_t)ch * PITCH + loff + p] =
                            fmaf(acc2[mb][sl][r], 0.000244140625f, acc1[mb][sl][r]) + rbv[sl];
                }
            }
        }
    }
}

// ---------------- 5 per-level sorts ----------------
__global__ __launch_bounds__(1024) void sort5_k(unsigned long long* keys, const int* cnt) {
    const int lvl = blockIdx.x;
    unsigned long long* kb = keys + (size_t)lvl * KEY_CAP;
    int n = cnt[lvl]; if (n > KEY_CAP) n = KEY_CAP;
    int m = 2; while (m < n) m <<= 1;
    __shared__ unsigned long long sk[8192];
    if (m <= 8192) {
        for (int i = threadIdx.x; i < m; i += 1024) sk[i] = (i < n) ? kb[i] : 0ull;
        __syncthreads();
        for (int k = 2; k <= m; k <<= 1)
            for (int j = k >> 1; j > 0; j >>= 1) {
                for (int i = threadIdx.x; i < m; i += 1024) {
                    int ixj = i ^ j;
                    if (ixj > i) {
                        unsigned long long a = sk[i], b = sk[ixj];
                        bool desc = (i & k) == 0;
                        if (desc ? (a < b) : (a > b)) { sk[i] = b; sk[ixj] = a; }
                    }
                }
                __syncthreads();
            }
        for (int i = threadIdx.x; i < m; i += 1024) kb[i] = sk[i];
    } else {
        for (int i = threadIdx.x; i < m; i += 1024) if (i >= n) kb[i] = 0ull;
        __syncthreads();
        for (int k = 2; k <= m; k <<= 1)
            for (int j = k >> 1; j > 0; j >>= 1) {
                for (int i = threadIdx.x; i < m; i += 1024) {
                    int ixj = i ^ j;
                    if (ixj > i) {
                        unsigned long long a = kb[i], b = kb[ixj];
                        bool desc = (i & k) == 0;
                        if (desc ? (a < b) : (a > b)) { kb[i] = b; kb[ixj] = a; }
                    }
                }
                __syncthreads();
            }
    }
}

// ---------------- emit top-1000 per level ----------------
__global__ void emit_k(const unsigned long long* __restrict__ keys, const int* __restrict__ cnt,
                       const float* __restrict__ regout, const float* __restrict__ anchors,
                       float* __restrict__ cs, float* __restrict__ cb, int* __restrict__ cl) {
#pragma clang fp contract(off)
    int r = blockIdx.x * 256 + threadIdx.x;
    if (r >= NCAND) return;
    int lvl = r / 1000, rr = r - lvl * 1000;
    int n = cnt[lvl]; if (n > KEY_CAP) n = KEY_CAP; if (n > 1000) n = 1000;
    float score = -1.0f, b0 = 0.f, b1 = 0.f, b2 = 0.f, b3 = 0.f;
    int label = 0;
    if (rr < n) {
        unsigned long long key = keys[(size_t)lvl * KEY_CAP + rr];
        score = __uint_as_float((unsigned)(key >> 32));
        unsigned flat = ~((unsigned)(key & 0xFFFFFFFFull));
        label = (int)(flat % NUM_CLASSES);
        int af = (int)(flat / NUM_CLASSES);
        int a = af % NUM_ANCH;
        int pix = af / NUM_ANCH;
        int gp = c_loff[lvl] + pix;
        float dx = regout[(size_t)(a * 4 + 0) * PITCH + gp];
        float dy = regout[(size_t)(a * 4 + 1) * PITCH + gp];
        float dw = regout[(size_t)(a * 4 + 2) * PITCH + gp];
        float dh = regout[(size_t)(a * 4 + 3) * PITCH + gp];
        const float* an = anchors + (size_t)(c_aoff[lvl] + af) * 4;
        float aw = an[2] - an[0];
        float ah = an[3] - an[1];
        float cx = an[0] + 0.5f * aw;
        float cy = an[1] + 0.5f * ah;
        dw = fminf(dw, BBOX_CLIP_F);
        dh = fminf(dh, BBOX_CLIP_F);
        float pcx = dx * aw + cx;
        float pcy = dy * ah + cy;
        float pw = expf(dw) * aw;
        float ph = expf(dh) * ah;
        b0 = fminf(fmaxf(pcx - 0.5f * pw, 0.0f), 512.0f);
        b1 = fminf(fmaxf(pcy - 0.5f * ph, 0.0f), 512.0f);
        b2 = fminf(fmaxf(pcx + 0.5f * pw, 0.0f), 512.0f);
        b3 = fminf(fmaxf(pcy + 0.5f * ph, 0.0f), 512.0f);
    }
    cs[r] = score;
    cb[(size_t)r * 4 + 0] = b0;
    cb[(size_t)r * 4 + 1] = b1;
    cb[(size_t)r * 4 + 2] = b2;
    cb[(size_t)r * 4 + 3] = b3;
    cl[r] = label;
}

// ---------------- global rank via per-level binary search ----------------
__global__ void rank_k(const float* __restrict__ cs, const float* __restrict__ cbx,
                       const int* __restrict__ cl, const int* __restrict__ cnt,
                       int* __restrict__ order, float* __restrict__ sbox,
                       float* __restrict__ sarea, int* __restrict__ nvp) {
#pragma clang fp contract(off)
    __shared__ int vls[5];
    int t = blockIdx.x * 256 + threadIdx.x;
    if (threadIdx.x < 5) {
        int n = cnt[threadIdx.x]; if (n > 1000) n = 1000;
        vls[threadIdx.x] = n;
    }
    __syncthreads();
    if (t >= NCAND) return;
    if (t == 0) *nvp = vls[0] + vls[1] + vls[2] + vls[3] + vls[4];
    int lvl = t / 1000, pos = t - lvl * 1000;
    if (pos >= vls[lvl]) return;                 // filler slot
    float s = cs[t];
    int rank = pos;
#pragma unroll
    for (int l2 = 0; l2 < 5; ++l2) {
        if (l2 == lvl) continue;
        int n = vls[l2];
        const float* seg = cs + l2 * 1000;       // descending
        int lo = 0, hi = n;
        if (l2 < lvl) {                          // count >= s
            while (lo < hi) { int mid = (lo + hi) >> 1; if (seg[mid] >= s) lo = mid + 1; else hi = mid; }
        } else {                                 // count > s
            while (lo < hi) { int mid = (lo + hi) >> 1; if (seg[mid] > s) lo = mid + 1; else hi = mid; }
        }
        rank += lo;
    }
    order[rank] = t;
    float off = (float)cl[t] * 513.0f;           // class spacing; cross-class IoU == 0 exactly
    float x1 = cbx[(size_t)t * 4 + 0] + off;
    float y1 = cbx[(size_t)t * 4 + 1] + off;
    float x2 = cbx[(size_t)t * 4 + 2] + off;
    float y2 = cbx[(size_t)t * 4 + 3] + off;
    sbox[(size_t)rank * 4 + 0] = x1;
    sbox[(size_t)rank * 4 + 1] = y1;
    sbox[(size_t)rank * 4 + 2] = x2;
    sbox[(size_t)rank * 4 + 3] = y2;
    sarea[rank] = (x2 - x1) * (y2 - y1);
}

// ---------------- IoU suppression bitmask over SORTED ranks ----------------
__global__ void mask_k(const float* __restrict__ sbox, const float* __restrict__ sarea,
                       const int* __restrict__ nvp, unsigned long long* __restrict__ mask) {
#pragma clang fp contract(off)
    int nv = *nvp;
    int t = blockIdx.x * 256 + threadIdx.x;
    if (t >= NCAND * 80) return;
    int i = t / 80, w = t - i * 80;
    if (i >= nv) return;
    float ix1 = sbox[(size_t)i * 4 + 0];
    float iy1 = sbox[(size_t)i * 4 + 1];
    float ix2 = sbox[(size_t)i * 4 + 2];
    float iy2 = sbox[(size_t)i * 4 + 3];
    float ai = sarea[i];
    unsigned long long bits = 0ull;
    int j0 = w * 64;
    for (int b = 0; b < 64; ++b) {
        int j = j0 + b;
        if (j < nv) {
            float jx1 = sbox[(size_t)j * 4 + 0];
            float jy1 = sbox[(size_t)j * 4 + 1];
            float jx2 = sbox[(size_t)j * 4 + 2];
            float jy2 = sbox[(size_t)j * 4 + 3];
            float aj = sarea[j];
            float ltx = fmaxf(ix1, jx1), lty = fmaxf(iy1, jy1);
            float rbx = fminf(ix2, jx2), rby = fminf(iy2, jy2);
            float wx = fmaxf(rbx - ltx, 0.0f), wy = fmaxf(rby - lty, 0.0f);
            float inter = wx * wy;
            float iou = inter / (ai + aj - inter + 1e-12f);
            if (iou > 0.5f) bits |= (1ull << b);
        }
    }
    mask[(size_t)i * 80 + w] = bits;
}

// ---------------- single-wave greedy sweep: tile-batched parallel row gather ----------------
__global__ __launch_bounds__(64) void sweep_k(const unsigned long long* __restrict__ mask,
        const int* __restrict__ nvp, int* __restrict__ accbuf, int* __restrict__ naccp) {
    const int l = threadIdx.x;
    int nv = *nvp; if (nv > NCAND) nv = NCAND;
    int nacc = 0;
    if (nv > 0) {
        unsigned long long sup0 = 0ull, sup1 = 0ull;
        int ntiles = (nv + 63) >> 6;
        bool done = false;
        for (int g0 = 0; g0 < ntiles && !done; g0 += 8) {
            int gcnt = ntiles - g0; if (gcnt > 8) gcnt = 8;
            unsigned long long ml[8];
#pragma unroll
            for (int g = 0; g < 8; ++g) {
                int t = g0 + g;
                int row = (t << 6) + l;
                ml[g] = (g < gcnt && row < nv) ? mask[(size_t)row * 80 + t] : 0ull;
            }
            for (int g = 0; g < gcnt && !done; ++g) {
                int t = g0 + g;
                unsigned long long cur = (t < 64)
                    ? (unsigned long long)__shfl((long long)sup0, t, 64)
                    : (unsigned long long)__shfl((long long)sup1, t - 64, 64);
                int lim = nv - (t << 6);
                unsigned long long valid = (lim >= 64) ? ~0ull : ((1ull << lim) - 1ull);
                unsigned long long rem = ~cur & valid;
                unsigned long long Aset = 0ull;
                while (rem) {
                    int k = __builtin_ctzll(rem);
                    Aset |= 1ull << k;
                    if (l == 0) accbuf[nacc] = (t << 6) + k;
                    ++nacc;
                    if (nacc == 300) { done = true; break; }
                    unsigned long long mlk = (unsigned long long)__shfl((long long)ml[g], k, 64);
                    cur |= mlk | (1ull << k);
                    rem = ~cur & valid;
                }
                if (!done) {
                    unsigned long long t2 = Aset;
                    while (t2) {
                        int i0 = __builtin_ctzll(t2); t2 &= t2 - 1;
                        int i1 = -1, i2 = -1, i3 = -1;
                        if (t2) { i1 = __builtin_ctzll(t2); t2 &= t2 - 1; }
                        if (t2) { i2 = __builtin_ctzll(t2); t2 &= t2 - 1; }
                        if (t2) { i3 = __builtin_ctzll(t2); t2 &= t2 - 1; }
                        size_t r0 = (size_t)((t << 6) + i0) * 80;
                        unsigned long long w0 = mask[r0 + l];
                        unsigned long long w1 = (i1 >= 0) ? mask[(size_t)((t << 6) + i1) * 80 + l] : 0ull;
                        unsigned long long w2 = (i2 >= 0) ? mask[(size_t)((t << 6) + i2) * 80 + l] : 0ull;
                        unsigned long long w3 = (i3 >= 0) ? mask[(size_t)((t << 6) + i3) * 80 + l] : 0ull;
                        sup0 |= w0 | w1 | w2 | w3;
                        if (l < 16) {
                            unsigned long long v0 = mask[r0 + 64 + l];
                            unsigned long long v1 = (i1 >= 0) ? mask[(size_t)((t << 6) + i1) * 80 + 64 + l] : 0ull;
                            unsigned long long v2 = (i2 >= 0) ? mask[(size_t)((t << 6) + i2) * 80 + 64 + l] : 0ull;
                            unsigned long long v3 = (i3 >= 0) ? mask[(size_t)((t << 6) + i3) * 80 + 64 + l] : 0ull;
                            sup1 |= v0 | v1 | v2 | v3;
                        }
                    }
                }
            }
        }
    }
    if (l == 0) *naccp = nacc;
}

// ---------------- fill outputs from accepted ranks ----------------
__global__ void fill_k(const float* __restrict__ cs, const float* __restrict__ cb,
                       const int* __restrict__ cl, const int* __restrict__ order,
                       const int* __restrict__ accbuf, const int* __restrict__ naccp,
                       float* __restrict__ out) {
    int t = blockIdx.x * 64 + threadIdx.x;
    if (t >= 300) return;
    int na = *naccp;
    if (t < na) {
        int c = order[accbuf[t]];
        out[t * 5 + 0] = cs[c];
        out[t * 5 + 1] = cb[(size_t)c * 4 + 0];
        out[t * 5 + 2] = cb[(size_t)c * 4 + 1];
        out[t * 5 + 3] = cb[(size_t)c * 4 + 2];
        out[t * 5 + 4] = cb[(size_t)c * 4 + 3];
        out[1500 + t] = (float)cl[c];
    } else {
        out[t * 5 + 0] = 0.0f; out[t * 5 + 1] = 0.0f; out[t * 5 + 2] = 0.0f;
        out[t * 5 + 3] = 0.0f; out[t * 5 + 4] = 0.0f;
        out[1500 + t] = -1.0f;
    }
}

// ---------------- host launch ----------------
extern "C" void kernel_launch(void* const* d_in, const int* in_sizes, int n_in,
                              void* d_out, int out_size, void* d_ws, size_t ws_size,
                              hipStream_t stream) {
    const float* f0 = (const float*)d_in[0];
    const float* f1 = (const float*)d_in[1];
    const float* f2 = (const float*)d_in[2];
    const float* f3 = (const float*)d_in[3];
    const float* f4 = (const float*)d_in[4];
    const float* anchors = (const float*)d_in[5];
    const float* ctw = (const float*)d_in[6];
    const float* ctb = (const float*)d_in[7];
    const float* cow = (const float*)d_in[8];
    const float* cob = (const float*)d_in[9];
    const float* rtw = (const float*)d_in[10];
    const float* rtb = (const float*)d_in[11];
    const float* row_ = (const float*)d_in[12];
    const float* rob = (const float*)d_in[13];
    float* out = (float*)d_out;

    char* base = (char*)d_ws;
    unsigned short* wf = (unsigned short*)base;
    unsigned short* C  = (unsigned short*)(base + 24772608);
    unsigned short* IN = (unsigned short*)(base + 30887936);
    unsigned short* A  = (unsigned short*)(base + 37003264);
    unsigned short* B  = (unsigned short*)(base + 43118592);
    int* cnt           = (int*)(base + 49233920);   // cnt[0..4], nv at [6], nacc at [7]
    int* nvp           = cnt + 6;
    int* naccp         = cnt + 7;
    float* cs    = (float*)(base + 0);              // wf head (dead after mhead)
    float* cbx   = (float*)(base + 32768);
    int*   cl    = (int*)(base + 131072);
    int*   order = (int*)(base + 163840);
    float* sbox  = (float*)(base + 262144);
    float* sarea = (float*)(base + 344064);
    int*   accbuf = (int*)(base + 368640);
    unsigned long long* keys = (unsigned long long*)A;          // A dead after layer 4
    float* regout            = (float*)(base + 37003264 + 2621440);
    unsigned long long* mask = (unsigned long long*)B;          // B dead after layer 4

    unsigned short* SL_clsL[4] = {wf + (size_t)168 * 73728, wf + (size_t)0 * 73728,
                                  wf + (size_t)16 * 73728,  wf + (size_t)32 * 73728};
    unsigned short* SL_regL[4] = {wf + (size_t)48 * 73728, wf + (size_t)64 * 73728,
                                  wf + (size_t)80 * 73728, wf + (size_t)96 * 73728};
    unsigned short* SL_clsH = wf + (size_t)112 * 73728;
    unsigned short* SL_regH = wf + (size_t)164 * 73728;

    hipMemsetAsync(C, 0, 4 * (size_t)ABUF_B, stream);   // zero C, IN, A, B (contiguous)
    hipMemsetAsync(cnt, 0, 32, stream);

    pad_k<<<(256 * PITCH + 255) / 256, 256, 0, stream>>>(f0, f1, f2, f3, f4, IN);
    wprep_k<<<(184 * 72 * 64 + 255) / 256, 256, 0, stream>>>(ctw, rtw, cow, row_, wf);

    // L1: (IN,IN)->(A,B)    [cls-L1 weights live where C will go]
    conv_t<<<86 * 8, 128, 0, stream>>>(IN, IN, A, B, SL_clsL[0], SL_regL[0], ctb, rtb);
    hipMemsetAsync(C, 0, (size_t)ABUF_B, stream);       // re-zero C (was weight data)
    // L2: (A,B)->(C,IN)
    conv_t<<<86 * 8, 128, 0, stream>>>(A, B, C, IN, SL_clsL[1], SL_regL[1], ctb + 256, rtb + 256);
    // L3: (C,IN)->(A,B)
    conv_t<<<86 * 8, 128, 0, stream>>>(C, IN, A, B, SL_clsL[2], SL_regL[2], ctb + 512, rtb + 512);
    // L4: (A,B)->(C,IN)
    conv_t<<<86 * 8, 128, 0, stream>>>(A, B, C, IN, SL_clsL[3], SL_regL[3], ctb + 768, rtb + 768);

    mhead_t<<<86 * 14, 128, 0, stream>>>(C, IN, SL_clsH, SL_regH, cob, rob, keys, cnt, regout);

    sort5_k<<<5, 1024, 0, stream>>>(keys, cnt);
    emit_k<<<(NCAND + 255) / 256, 256, 0, stream>>>(keys, cnt, regout, anchors, cs, cbx, cl);
    rank_k<<<(NCAND + 255) / 256, 256, 0, stream>>>(cs, cbx, cl, cnt, order, sbox, sarea, nvp);
    mask_k<<<(NCAND * 80 + 255) / 256, 256, 0, stream>>>(sbox, sarea, nvp, mask);
    sweep_k<<<1, 64, 0, stream>>>(mask, nvp, accbuf, naccp);
    fill_k<<<5, 64, 0, stream>>>(cs, cbx, cl, order, accbuf, naccp, out);
}

// Round 10
// 617.646 us; speedup vs baseline: 1.1015x; 1.1015x over previous
//
#include <hip/hip_runtime.h>
#include <hip/hip_bf16.h>
#include <math.h>

#define CIN 256
#define NUM_CLASSES 91
#define NUM_ANCH 9
#define KEY_CAP 65536
#define NCAND 5000
#define BBOX_CLIP_F 4.135166556742356f
#define CLS_THRESH 0.05f
#define PITCH 5456
#define PP_TOT 5972
#define PLANE_E 1528832      // ushorts per plane (8*5972*32)
#define PLANE_B 3057664      // bytes per plane
#define ABUF_B  6115328      // bytes per act buffer (hi+lo plane)
#define SLB     147456       // bytes per 16-cout weight-frag slice
#define HPHASE  13312        // LDS bytes per hi phase (13 x 1024)

typedef __attribute__((ext_vector_type(4))) float f4;
typedef _Float16 h8 __attribute__((ext_vector_type(8)));

#define MFMA(a,b,c) __builtin_amdgcn_mfma_f32_16x16x32_f16(a,b,c,0,0,0)

__constant__ int c_wsh[5]  = {6,5,4,3,2};
__constant__ int c_hw[5]   = {4096,1024,256,64,16};
__constant__ int c_wp[5]   = {66,34,18,10,6};
__constant__ int c_poff[5] = {0,4356,5512,5836,5936};
__constant__ int c_slen[5] = {198,136,108,100,36};   // strip len for 64-px tiles
__constant__ int c_loff[5] = {0,4096,5120,5376,5440};
__constant__ int c_aoff[5] = {0,36864,46080,48384,48960};
// wf slice ranges: clsL2,clsL3,clsL4,regL1,regL2,regL3,regL4,clsHead(52),regHead(4),clsL1(16)
__constant__ int s_cum[11] = {0,16,32,48,64,80,96,112,164,168,184};

__device__ __forceinline__ unsigned short f16r(float f) {
    _Float16 h = (_Float16)f;
    return __builtin_bit_cast(unsigned short, h);
}
__device__ __forceinline__ float f16tof(unsigned short u) {
    return (float)__builtin_bit_cast(_Float16, u);
}
// split v = h + l/4096, h zero-guarded against f16 denormal flush, l pre-scaled x4096
__device__ __forceinline__ void split16(float v, unsigned short& h, unsigned short& l) {
    unsigned short hh = (fabsf(v) < 6.103515625e-05f) ? (unsigned short)0 : f16r(v);
    h = hh;
    l = f16r((v - f16tof(hh)) * 4096.0f);
}
__device__ __forceinline__ void gl_lds(const void* g, void* l) {
    __builtin_amdgcn_global_load_lds((const __attribute__((address_space(1))) void*)g,
                                     (__attribute__((address_space(3))) void*)l, 16, 0, 0);
}
__device__ __forceinline__ void tile_geom(int tile, int& lvl, int& px0, int& y0) {
    if (tile < 64)      { lvl = 0; px0 = tile << 6; y0 = tile; }
    else if (tile < 80) { lvl = 1; int j = tile - 64; px0 = j << 6; y0 = j << 1; }
    else if (tile < 84) { lvl = 2; int j = tile - 80; px0 = j << 6; y0 = j << 2; }
    else if (tile == 84){ lvl = 3; px0 = 0; y0 = 0; }
    else                { lvl = 4; px0 = 0; y0 = 0; }
}

// ---------------- pad + split + chunk the input pyramid ----------------
__global__ void pad_k(const float* __restrict__ f0, const float* __restrict__ f1,
                      const float* __restrict__ f2, const float* __restrict__ f3,
                      const float* __restrict__ f4, unsigned short* __restrict__ IN) {
    int gid = blockIdx.x * 256 + threadIdx.x;
    if (gid >= 256 * PITCH) return;
    int cin = gid / PITCH, g = gid - cin * PITCH;
    int lvl = (g < 4096) ? 0 : (g < 5120) ? 1 : (g < 5376) ? 2 : (g < 5440) ? 3 : 4;
    const float* f = (lvl == 0) ? f0 : (lvl == 1) ? f1 : (lvl == 2) ? f2 : (lvl == 3) ? f3 : f4;
    int pix = g - c_loff[lvl];
    int wsh = c_wsh[lvl];
    int y = pix >> wsh, x = pix & ((1 << wsh) - 1);
    float v = f[(size_t)cin * c_hw[lvl] + pix];
    unsigned short h, l;
    split16(v, h, l);
    size_t idx = ((size_t)(cin >> 5) * PP_TOT + c_poff[lvl] + (size_t)(y + 1) * c_wp[lvl] + x + 1) * 32 + (cin & 31);
    IN[idx] = h;
    IN[PLANE_E + idx] = l;
}

// ---------------- weight fragment prep (f16 hi + scaled-lo, MFMA B-frag order) ----------------
__global__ void wprep_k(const float* __restrict__ ctw, const float* __restrict__ rtw,
                        const float* __restrict__ cow, const float* __restrict__ row_,
                        unsigned short* __restrict__ wf) {
    int gid = blockIdx.x * 256 + threadIdx.x;
    if (gid >= 184 * 72 * 64) return;
    int lane = gid & 63;
    int t = gid >> 6;
    int tap = t % 9;
    int t2 = t / 9;
    int chunk = t2 & 7;
    int cbg = t2 >> 3;
    int r = 0;
#pragma unroll
    for (int i = 1; i <= 10; ++i) if (cbg >= s_cum[i]) r = i;
    int cbl = cbg - s_cum[r];
    const float* src;
    int coutCnt;
    if (r < 3)       { src = ctw + (size_t)(r + 1) * 589824; coutCnt = 256; }
    else if (r < 7)  { src = rtw + (size_t)(r - 3) * 589824; coutCnt = 256; }
    else if (r == 7) { src = cow; coutCnt = 819; }
    else if (r == 8) { src = row_; coutCnt = 36; }
    else             { src = ctw; coutCnt = 256; }
    int cout = cbl * 16 + (lane & 15);
    int q = lane >> 4;
    unsigned short H[8], L[8];
#pragma unroll
    for (int j = 0; j < 8; ++j) {
        int cin = chunk * 32 + q * 8 + j;
        float v = (cout < coutCnt) ? src[((size_t)cout * 256 + cin) * 9 + tap] : 0.0f;
        split16(v, H[j], L[j]);
    }
    size_t off = (size_t)cbg * 73728 + (size_t)(chunk * 9 + tap) * 1024 + (size_t)lane * 8;
#pragma unroll
    for (int j = 0; j < 8; ++j) { wf[off + j] = H[j]; wf[off + 512 + j] = L[j]; }
}

// ---------------- MFMA K-loop: wave = 32px x 32cout, hi-plane dbuf LDS,
// ---------------- lo-plane + B read from global with register next-tap prefetch
__device__ __forceinline__ void kloop(const unsigned short* __restrict__ src,
        const char* __restrict__ wf0, char* sm, int wid, int lane, int quad,
        int s_base, int s_len, int Wp, const int relrow[2], f4 acc1[2][2], f4 acc2[2][2]) {
    const char* wp = wf0 + lane * 16;
    int nc = (s_len * 64 + 1023) >> 10;
    const char* gbase = (const char*)src;
    {   // stage hi chunk 0 into phase 0
        const char* g = gbase + (size_t)s_base * 64;
        for (int c = wid; c < nc; c += 4)
            gl_lds(g + (size_t)c * 1024 + (size_t)lane * 16, sm + c * 1024);
    }
    // lo-plane global base pointers (chunk 0)
    const char* lo0 = gbase + PLANE_B + (size_t)(s_base + relrow[0]) * 64 + quad * 16;
    const char* lo1 = gbase + PLANE_B + (size_t)(s_base + relrow[1]) * 64 + quad * 16;
    const int t00 = (-1 - Wp) * 64;   // tap-0 offset
    // prefetch B(kt=0) and al(tap=0)
    h8 bh0 = *(const h8*)(wp);
    h8 bl0 = *(const h8*)(wp + 1024);
    h8 bh1 = *(const h8*)(wp + SLB);
    h8 bl1 = *(const h8*)(wp + SLB + 1024);
    h8 al0 = *(const h8*)(lo0 + t00);
    h8 al1 = *(const h8*)(lo1 + t00);
    __syncthreads();
    int sA0 = relrow[0] * 64 + (quad << 4);
    int sA1 = relrow[1] * 64 + (quad << 4);
    for (int chunk = 0; chunk < 8; ++chunk) {
        char* smc = sm + (chunk & 1) * HPHASE;
        if (chunk < 7) {   // issue next-chunk hi staging BEFORE compute
            char* smn = sm + ((chunk & 1) ^ 1) * HPHASE;
            const char* g = gbase + ((size_t)(chunk + 1) * PP_TOT + s_base) * 64;
            for (int c = wid; c < nc; c += 4)
                gl_lds(g + (size_t)c * 1024 + (size_t)lane * 16, smn + c * 1024);
        }
        const char* lo0n = (chunk < 7) ? lo0 + (size_t)PP_TOT * 64 : lo0;
        const char* lo1n = (chunk < 7) ? lo1 + (size_t)PP_TOT * 64 : lo1;
#pragma unroll
        for (int tap = 0; tap < 9; ++tap) {
            int kt = chunk * 9 + tap;
            int wo2 = ((kt < 71) ? kt + 1 : kt) * 2048;   // next-tap B prefetch (clamped)
            h8 nh0 = *(const h8*)(wp + wo2);
            h8 nl0 = *(const h8*)(wp + wo2 + 1024);
            h8 nh1 = *(const h8*)(wp + SLB + wo2);
            h8 nl1 = *(const h8*)(wp + SLB + wo2 + 1024);
            // next-tap (or next-chunk tap0) lo fragments from global
            h8 na0, na1;
            if (tap < 8) {
                int tn = (((tap + 1) / 3) - 1) * Wp + ((tap + 1) % 3) - 1;
                na0 = *(const h8*)(lo0 + tn * 64);
                na1 = *(const h8*)(lo1 + tn * 64);
            } else {
                na0 = *(const h8*)(lo0n + t00);
                na1 = *(const h8*)(lo1n + t00);
            }
            int so = (((tap / 3) - 1) * Wp + (tap % 3) - 1) * 64;
            h8 ah0 = *(const h8*)(smc + sA0 + so);
            h8 ah1 = *(const h8*)(smc + sA1 + so);
            acc1[0][0] = MFMA(ah0, bh0, acc1[0][0]);
            acc2[0][0] = MFMA(al0, bh0, acc2[0][0]);
            acc2[0][0] = MFMA(ah0, bl0, acc2[0][0]);
            acc1[1][0] = MFMA(ah1, bh0, acc1[1][0]);
            acc2[1][0] = MFMA(al1, bh0, acc2[1][0]);
            acc2[1][0] = MFMA(ah1, bl0, acc2[1][0]);
            acc1[0][1] = MFMA(ah0, bh1, acc1[0][1]);
            acc2[0][1] = MFMA(al0, bh1, acc2[0][1]);
            acc2[0][1] = MFMA(ah0, bl1, acc2[0][1]);
            acc1[1][1] = MFMA(ah1, bh1, acc1[1][1]);
            acc2[1][1] = MFMA(al1, bh1, acc2[1][1]);
            acc2[1][1] = MFMA(ah1, bl1, acc2[1][1]);
            bh0 = nh0; bl0 = nl0; bh1 = nh1; bl1 = nl1;
            al0 = na0; al1 = na1;
        }
        lo0 = lo0n; lo1 = lo1n;
        __syncthreads();
    }
}

// ---------------- fused tower layer: 64px x 64cout blocks (4 waves of 32px x 32cout) ----------------
__global__ __launch_bounds__(256, 4) void conv_t(
        const unsigned short* __restrict__ srcC, const unsigned short* __restrict__ srcR,
        unsigned short* __restrict__ dstC, unsigned short* __restrict__ dstR,
        const unsigned short* __restrict__ wfC, const unsigned short* __restrict__ wfR,
        const float* __restrict__ bC, const float* __restrict__ bR) {
    __shared__ __align__(16) char sm[2 * HPHASE];
    int tid = threadIdx.x, lane = tid & 63, wid = tid >> 6;
    int quad = lane >> 4, l16 = lane & 15;
    int bx = blockIdx.x;
    int cb = bx & 3, tower = (bx >> 2) & 1, tile = bx >> 3;
    const unsigned short* src = tower ? srcR : srcC;
    unsigned short* dst = tower ? dstR : dstC;
    const unsigned short* wfx = tower ? wfR : wfC;
    const float* bias = tower ? bR : bC;

    int lvl, px0, y0;
    tile_geom(tile, lvl, px0, y0);
    int wsh = c_wsh[lvl], HW = c_hw[lvl], Wp = c_wp[lvl];
    int poff = c_poff[lvl];
    int s_base = poff + y0 * Wp, s_len = c_slen[lvl];
    int Mh = (wid & 1) * 32, Nh32 = wid >> 1;      // wave: 32 px x 32 couts (2 slices)

    int relrow[2];
#pragma unroll
    for (int mb = 0; mb < 2; ++mb) {
        int p = px0 + Mh + mb * 16 + l16;
        if (p >= HW) p = HW - 1;
        int y = p >> wsh, x = p & ((1 << wsh) - 1);
        relrow[mb] = (y - y0 + 1) * Wp + x + 1;
    }
    f4 acc1[2][2], acc2[2][2];
#pragma unroll
    for (int mb = 0; mb < 2; ++mb)
#pragma unroll
        for (int sl = 0; sl < 2; ++sl) { acc1[mb][sl] = (f4)0.0f; acc2[mb][sl] = (f4)0.0f; }

    const char* wf0 = (const char*)wfx + (size_t)(cb * 4 + Nh32 * 2) * SLB;
    kloop(src, wf0, sm, wid, lane, quad, s_base, s_len, Wp, relrow, acc1, acc2);

    int cbase = cb * 64 + Nh32 * 32;
    float bv[2];
    bv[0] = bias[cbase + l16];
    bv[1] = bias[cbase + 16 + l16];
#pragma unroll
    for (int mb = 0; mb < 2; ++mb) {
        int pb = px0 + Mh + mb * 16 + quad * 4;
#pragma unroll
        for (int r = 0; r < 4; ++r) {
            int p = pb + r;
            bool valid = p < HW;
            int pc = valid ? p : 0;
            int y = pc >> wsh, x = pc & ((1 << wsh) - 1);
            size_t ppix = poff + (size_t)(y + 1) * Wp + x + 1;
#pragma unroll
            for (int sl = 0; sl < 2; ++sl) {
                int coutg = cbase + sl * 16 + l16;
                float v = fmaf(acc2[mb][sl][r], 0.000244140625f, acc1[mb][sl][r]) + bv[sl];
                v = fmaxf(v, 0.0f);
                unsigned short h, l;
                split16(v, h, l);
                size_t idx = ((size_t)(coutg >> 5) * PP_TOT + ppix) * 32 + (coutg & 31);
                if (valid) { dst[idx] = h; dst[PLANE_E + idx] = l; }
            }
        }
    }
}

// ---------------- fused heads: cls (sigmoid+collect fused) + reg ----------------
__global__ __launch_bounds__(256, 4) void mhead_t(
        const unsigned short* __restrict__ srcC, const unsigned short* __restrict__ srcR,
        const unsigned short* __restrict__ wfCls, const unsigned short* __restrict__ wfReg,
        const float* __restrict__ cob, const float* __restrict__ rob,
        unsigned long long* __restrict__ keys, int* __restrict__ cnt,
        float* __restrict__ regout) {
    __shared__ __align__(16) char sm[2 * HPHASE];
    int tid = threadIdx.x, lane = tid & 63, wid = tid >> 6;
    int quad = lane >> 4, l16 = lane & 15;
    int bx = blockIdx.x, tile = bx / 14, sub = bx - tile * 14;
    bool isCls = sub < 13;

    int lvl, px0, y0;
    tile_geom(tile, lvl, px0, y0);
    int wsh = c_wsh[lvl], HW = c_hw[lvl], Wp = c_wp[lvl];
    int poff = c_poff[lvl];
    int s_base = poff + y0 * Wp, s_len = c_slen[lvl];
    int Mh = (wid & 1) * 32, Nh32 = wid >> 1;      // wave: 32 px x 32 couts

    int relrow[2];
#pragma unroll
    for (int mb = 0; mb < 2; ++mb) {
        int p = px0 + Mh + mb * 16 + l16;
        if (p >= HW) p = HW - 1;
        int y = p >> wsh, x = p & ((1 << wsh) - 1);
        relrow[mb] = (y - y0 + 1) * Wp + x + 1;
    }
    f4 acc1[2][2], acc2[2][2];
#pragma unroll
    for (int mb = 0; mb < 2; ++mb)
#pragma unroll
        for (int sl = 0; sl < 2; ++sl) { acc1[mb][sl] = (f4)0.0f; acc2[mb][sl] = (f4)0.0f; }

    const unsigned short* src = isCls ? srcC : srcR;
    // cls: sub s covers couts [s*64, s*64+64) over 52 slices (tail zero-padded in wf)
    // reg: couts [0,64), real 36, rest zero-padded in wf
    const char* wf0 = isCls ? (const char*)wfCls + (size_t)(sub * 4 + Nh32 * 2) * SLB
                            : (const char*)wfReg + (size_t)(Nh32 * 2) * SLB;
    kloop(src, wf0, sm, wid, lane, quad, s_base, s_len, Wp, relrow, acc1, acc2);

    if (isCls) {
        int chb = sub * 64 + Nh32 * 32;
        float cbv[2];
#pragma unroll
        for (int sl = 0; sl < 2; ++sl) {
            int ch = chb + sl * 16 + l16;
            cbv[sl] = (ch < 819) ? cob[ch] : 0.0f;
        }
#pragma unroll
        for (int mb = 0; mb < 2; ++mb) {
            int pb = px0 + Mh + mb * 16 + quad * 4;
#pragma unroll
            for (int r = 0; r < 4; ++r) {
                int p = pb + r;
                bool valid = p < HW;
#pragma unroll
                for (int sl = 0; sl < 2; ++sl) {
                    int ch = chb + sl * 16 + l16;
                    if (valid && ch < 819) {
                        float lg = fmaf(acc2[mb][sl][r], 0.000244140625f, acc1[mb][sl][r]) + cbv[sl];
                        float s = 1.0f / (1.0f + expf(-lg));
                        if (s > CLS_THRESH) {
                            int a = ch / NUM_CLASSES;
                            int cls = ch - a * NUM_CLASSES;
                            unsigned flat = (unsigned)((p * NUM_ANCH + a) * NUM_CLASSES + cls);
                            int pos = atomicAdd(cnt + lvl, 1);
                            if (pos < KEY_CAP)
                                keys[(size_t)lvl * KEY_CAP + pos] =
                                    ((unsigned long long)__float_as_uint(s) << 32) |
                                    (unsigned long long)(~flat);
                        }
                    }
                }
            }
        }
    } else {
        int chb = Nh32 * 32;
        float rbv[2];
#pragma unroll
        for (int sl = 0; sl < 2; ++sl) {
            int ch = chb + sl * 16 + l16;
            rbv[sl] = (ch < 36) ? rob[ch] : 0.0f;
        }
        int loff = c_loff[lvl];
#pragma unroll
        for (int mb = 0; mb < 2; ++mb) {
            int pb = px0 + Mh + mb * 16 + quad * 4;
#pragma unroll
            for (int r = 0; r < 4; ++r) {
                int p = pb + r;
                bool valid = p < HW;
#pragma unroll
                for (int sl = 0; sl < 2; ++sl) {
                    int ch = chb + sl * 16 + l16;
                    if (valid && ch < 36)
                        regout[(size_t)ch * PITCH + loff + p] =
                            fmaf(acc2[mb][sl][r], 0.000244140625f, acc1[mb][sl][r]) + rbv[sl];
                }
            }
        }
    }
}

// ---------------- 5 per-level sorts ----------------
__global__ __launch_bounds__(1024) void sort5_k(unsigned long long* keys, const int* cnt) {
    const int lvl = blockIdx.x;
    unsigned long long* kb = keys + (size_t)lvl * KEY_CAP;
    int n = cnt[lvl]; if (n > KEY_CAP) n = KEY_CAP;
    int m = 2; while (m < n) m <<= 1;
    __shared__ unsigned long long sk[8192];
    if (m <= 8192) {
        for (int i = threadIdx.x; i < m; i += 1024) sk[i] = (i < n) ? kb[i] : 0ull;
        __syncthreads();
        for (int k = 2; k <= m; k <<= 1)
            for (int j = k >> 1; j > 0; j >>= 1) {
                for (int i = threadIdx.x; i < m; i += 1024) {
                    int ixj = i ^ j;
                    if (ixj > i) {
                        unsigned long long a = sk[i], b = sk[ixj];
                        bool desc = (i & k) == 0;
                        if (desc ? (a < b) : (a > b)) { sk[i] = b; sk[ixj] = a; }
                    }
                }
                __syncthreads();
            }
        for (int i = threadIdx.x; i < m; i += 1024) kb[i] = sk[i];
    } else {
        for (int i = threadIdx.x; i < m; i += 1024) if (i >= n) kb[i] = 0ull;
        __syncthreads();
        for (int k = 2; k <= m; k <<= 1)
            for (int j = k >> 1; j > 0; j >>= 1) {
                for (int i = threadIdx.x; i < m; i += 1024) {
                    int ixj = i ^ j;
                    if (ixj > i) {
                        unsigned long long a = kb[i], b = kb[ixj];
                        bool desc = (i & k) == 0;
                        if (desc ? (a < b) : (a > b)) { kb[i] = b; kb[ixj] = a; }
                    }
                }
                __syncthreads();
            }
    }
}

// ---------------- emit top-1000 per level ----------------
__global__ void emit_k(const unsigned long long* __restrict__ keys, const int* __restrict__ cnt,
                       const float* __restrict__ regout, const float* __restrict__ anchors,
                       float* __restrict__ cs, float* __restrict__ cb, int* __restrict__ cl) {
#pragma clang fp contract(off)
    int r = blockIdx.x * 256 + threadIdx.x;
    if (r >= NCAND) return;
    int lvl = r / 1000, rr = r - lvl * 1000;
    int n = cnt[lvl]; if (n > KEY_CAP) n = KEY_CAP; if (n > 1000) n = 1000;
    float score = -1.0f, b0 = 0.f, b1 = 0.f, b2 = 0.f, b3 = 0.f;
    int label = 0;
    if (rr < n) {
        unsigned long long key = keys[(size_t)lvl * KEY_CAP + rr];
        score = __uint_as_float((unsigned)(key >> 32));
        unsigned flat = ~((unsigned)(key & 0xFFFFFFFFull));
        label = (int)(flat % NUM_CLASSES);
        int af = (int)(flat / NUM_CLASSES);
        int a = af % NUM_ANCH;
        int pix = af / NUM_ANCH;
        int gp = c_loff[lvl] + pix;
        float dx = regout[(size_t)(a * 4 + 0) * PITCH + gp];
        float dy = regout[(size_t)(a * 4 + 1) * PITCH + gp];
        float dw = regout[(size_t)(a * 4 + 2) * PITCH + gp];
        float dh = regout[(size_t)(a * 4 + 3) * PITCH + gp];
        const float* an = anchors + (size_t)(c_aoff[lvl] + af) * 4;
        float aw = an[2] - an[0];
        float ah = an[3] - an[1];
        float cx = an[0] + 0.5f * aw;
        float cy = an[1] + 0.5f * ah;
        dw = fminf(dw, BBOX_CLIP_F);
        dh = fminf(dh, BBOX_CLIP_F);
        float pcx = dx * aw + cx;
        float pcy = dy * ah + cy;
        float pw = expf(dw) * aw;
        float ph = expf(dh) * ah;
        b0 = fminf(fmaxf(pcx - 0.5f * pw, 0.0f), 512.0f);
        b1 = fminf(fmaxf(pcy - 0.5f * ph, 0.0f), 512.0f);
        b2 = fminf(fmaxf(pcx + 0.5f * pw, 0.0f), 512.0f);
        b3 = fminf(fmaxf(pcy + 0.5f * ph, 0.0f), 512.0f);
    }
    cs[r] = score;
    cb[(size_t)r * 4 + 0] = b0;
    cb[(size_t)r * 4 + 1] = b1;
    cb[(size_t)r * 4 + 2] = b2;
    cb[(size_t)r * 4 + 3] = b3;
    cl[r] = label;
}

// ---------------- global rank via per-level binary search ----------------
__global__ void rank_k(const float* __restrict__ cs, const float* __restrict__ cbx,
                       const int* __restrict__ cl, const int* __restrict__ cnt,
                       int* __restrict__ order, float* __restrict__ sbox,
                       float* __restrict__ sarea, int* __restrict__ nvp) {
#pragma clang fp contract(off)
    __shared__ int vls[5];
    int t = blockIdx.x * 256 + threadIdx.x;
    if (threadIdx.x < 5) {
        int n = cnt[threadIdx.x]; if (n > 1000) n = 1000;
        vls[threadIdx.x] = n;
    }
    __syncthreads();
    if (t >= NCAND) return;
    if (t == 0) *nvp = vls[0] + vls[1] + vls[2] + vls[3] + vls[4];
    int lvl = t / 1000, pos = t - lvl * 1000;
    if (pos >= vls[lvl]) return;                 // filler slot
    float s = cs[t];
    int rank = pos;
#pragma unroll
    for (int l2 = 0; l2 < 5; ++l2) {
        if (l2 == lvl) continue;
        int n = vls[l2];
        const float* seg = cs + l2 * 1000;       // descending
        int lo = 0, hi = n;
        if (l2 < lvl) {                          // count >= s
            while (lo < hi) { int mid = (lo + hi) >> 1; if (seg[mid] >= s) lo = mid + 1; else hi = mid; }
        } else {                                 // count > s
            while (lo < hi) { int mid = (lo + hi) >> 1; if (seg[mid] > s) lo = mid + 1; else hi = mid; }
        }
        rank += lo;
    }
    order[rank] = t;
    float off = (float)cl[t] * 513.0f;           // class spacing; cross-class IoU == 0 exactly
    float x1 = cbx[(size_t)t * 4 + 0] + off;
    float y1 = cbx[(size_t)t * 4 + 1] + off;
    float x2 = cbx[(size_t)t * 4 + 2] + off;
    float y2 = cbx[(size_t)t * 4 + 3] + off;
    sbox[(size_t)rank * 4 + 0] = x1;
    sbox[(size_t)rank * 4 + 1] = y1;
    sbox[(size_t)rank * 4 + 2] = x2;
    sbox[(size_t)rank * 4 + 3] = y2;
    sarea[rank] = (x2 - x1) * (y2 - y1);
}

// ---------------- IoU suppression bitmask over SORTED ranks ----------------
__global__ void mask_k(const float* __restrict__ sbox, const float* __restrict__ sarea,
                       const int* __restrict__ nvp, unsigned long long* __restrict__ mask) {
#pragma clang fp contract(off)
    int nv = *nvp;
    int t = blockIdx.x * 256 + threadIdx.x;
    if (t >= NCAND * 80) return;
    int i = t / 80, w = t - i * 80;
    if (i >= nv) return;
    float ix1 = sbox[(size_t)i * 4 + 0];
    float iy1 = sbox[(size_t)i * 4 + 1];
    float ix2 = sbox[(size_t)i * 4 + 2];
    float iy2 = sbox[(size_t)i * 4 + 3];
    float ai = sarea[i];
    unsigned long long bits = 0ull;
    int j0 = w * 64;
    for (int b = 0; b < 64; ++b) {
        int j = j0 + b;
        if (j < nv) {
            float jx1 = sbox[(size_t)j * 4 + 0];
            float jy1 = sbox[(size_t)j * 4 + 1];
            float jx2 = sbox[(size_t)j * 4 + 2];
            float jy2 = sbox[(size_t)j * 4 + 3];
            float aj = sarea[j];
            float ltx = fmaxf(ix1, jx1), lty = fmaxf(iy1, jy1);
            float rbx = fminf(ix2, jx2), rby = fminf(iy2, jy2);
            float wx = fmaxf(rbx - ltx, 0.0f), wy = fmaxf(rby - lty, 0.0f);
            float inter = wx * wy;
            float iou = inter / (ai + aj - inter + 1e-12f);
            if (iou > 0.5f) bits |= (1ull << b);
        }
    }
    mask[(size_t)i * 80 + w] = bits;
}

// ---------------- single-wave greedy sweep: tile-batched parallel row gather ----------------
__global__ __launch_bounds__(64) void sweep_k(const unsigned long long* __restrict__ mask,
        const int* __restrict__ nvp, int* __restrict__ accbuf, int* __restrict__ naccp) {
    const int l = threadIdx.x;
    int nv = *nvp; if (nv > NCAND) nv = NCAND;
    int nacc = 0;
    if (nv > 0) {
        unsigned long long sup0 = 0ull, sup1 = 0ull;
        int ntiles = (nv + 63) >> 6;
        bool done = false;
        for (int g0 = 0; g0 < ntiles && !done; g0 += 8) {
            int gcnt = ntiles - g0; if (gcnt > 8) gcnt = 8;
            unsigned long long ml[8];
#pragma unroll
            for (int g = 0; g < 8; ++g) {
                int t = g0 + g;
                int row = (t << 6) + l;
                ml[g] = (g < gcnt && row < nv) ? mask[(size_t)row * 80 + t] : 0ull;
            }
            for (int g = 0; g < gcnt && !done; ++g) {
                int t = g0 + g;
                unsigned long long cur = (t < 64)
                    ? (unsigned long long)__shfl((long long)sup0, t, 64)
                    : (unsigned long long)__shfl((long long)sup1, t - 64, 64);
                int lim = nv - (t << 6);
                unsigned long long valid = (lim >= 64) ? ~0ull : ((1ull << lim) - 1ull);
                unsigned long long rem = ~cur & valid;
                unsigned long long Aset = 0ull;
                while (rem) {
                    int k = __builtin_ctzll(rem);
                    Aset |= 1ull << k;
                    if (l == 0) accbuf[nacc] = (t << 6) + k;
                    ++nacc;
                    if (nacc == 300) { done = true; break; }
                    unsigned long long mlk = (unsigned long long)__shfl((long long)ml[g], k, 64);
                    cur |= mlk | (1ull << k);
                    rem = ~cur & valid;
                }
                if (!done) {
                    unsigned long long t2 = Aset;
                    while (t2) {
                        int i0 = __builtin_ctzll(t2); t2 &= t2 - 1;
                        int i1 = -1, i2 = -1, i3 = -1;
                        if (t2) { i1 = __builtin_ctzll(t2); t2 &= t2 - 1; }
                        if (t2) { i2 = __builtin_ctzll(t2); t2 &= t2 - 1; }
                        if (t2) { i3 = __builtin_ctzll(t2); t2 &= t2 - 1; }
                        size_t r0 = (size_t)((t << 6) + i0) * 80;
                        unsigned long long w0 = mask[r0 + l];
                        unsigned long long w1 = (i1 >= 0) ? mask[(size_t)((t << 6) + i1) * 80 + l] : 0ull;
                        unsigned long long w2 = (i2 >= 0) ? mask[(size_t)((t << 6) + i2) * 80 + l] : 0ull;
                        unsigned long long w3 = (i3 >= 0) ? mask[(size_t)((t << 6) + i3) * 80 + l] : 0ull;
                        sup0 |= w0 | w1 | w2 | w3;
                        if (l < 16) {
                            unsigned long long v0 = mask[r0 + 64 + l];
                            unsigned long long v1 = (i1 >= 0) ? mask[(size_t)((t << 6) + i1) * 80 + 64 + l] : 0ull;
                            unsigned long long v2 = (i2 >= 0) ? mask[(size_t)((t << 6) + i2) * 80 + 64 + l] : 0ull;
                            unsigned long long v3 = (i3 >= 0) ? mask[(size_t)((t << 6) + i3) * 80 + 64 + l] : 0ull;
                            sup1 |= v0 | v1 | v2 | v3;
                        }
                    }
                }
            }
        }
    }
    if (l == 0) *naccp = nacc;
}

// ---------------- fill outputs from accepted ranks ----------------
__global__ void fill_k(const float* __restrict__ cs, const float* __restrict__ cb,
                       const int* __restrict__ cl, const int* __restrict__ order,
                       const int* __restrict__ accbuf, const int* __restrict__ naccp,
                       float* __restrict__ out) {
    int t = blockIdx.x * 64 + threadIdx.x;
    if (t >= 300) return;
    int na = *naccp;
    if (t < na) {
        int c = order[accbuf[t]];
        out[t * 5 + 0] = cs[c];
        out[t * 5 + 1] = cb[(size_t)c * 4 + 0];
        out[t * 5 + 2] = cb[(size_t)c * 4 + 1];
        out[t * 5 + 3] = cb[(size_t)c * 4 + 2];
        out[t * 5 + 4] = cb[(size_t)c * 4 + 3];
        out[1500 + t] = (float)cl[c];
    } else {
        out[t * 5 + 0] = 0.0f; out[t * 5 + 1] = 0.0f; out[t * 5 + 2] = 0.0f;
        out[t * 5 + 3] = 0.0f; out[t * 5 + 4] = 0.0f;
        out[1500 + t] = -1.0f;
    }
}

// ---------------- host launch ----------------
extern "C" void kernel_launch(void* const* d_in, const int* in_sizes, int n_in,
                              void* d_out, int out_size, void* d_ws, size_t ws_size,
                              hipStream_t stream) {
    const float* f0 = (const float*)d_in[0];
    const float* f1 = (const float*)d_in[1];
    const float* f2 = (const float*)d_in[2];
    const float* f3 = (const float*)d_in[3];
    const float* f4 = (const float*)d_in[4];
    const float* anchors = (const float*)d_in[5];
    const float* ctw = (const float*)d_in[6];
    const float* ctb = (const float*)d_in[7];
    const float* cow = (const float*)d_in[8];
    const float* cob = (const float*)d_in[9];
    const float* rtw = (const float*)d_in[10];
    const float* rtb = (const float*)d_in[11];
    const float* row_ = (const float*)d_in[12];
    const float* rob = (const float*)d_in[13];
    float* out = (float*)d_out;

    char* base = (char*)d_ws;
    unsigned short* wf = (unsigned short*)base;
    unsigned short* C  = (unsigned short*)(base + 24772608);
    unsigned short* IN = (unsigned short*)(base + 30887936);
    unsigned short* A  = (unsigned short*)(base + 37003264);
    unsigned short* B  = (unsigned short*)(base + 43118592);
    int* cnt           = (int*)(base + 49233920);   // cnt[0..4], nv at [6], nacc at [7]
    int* nvp           = cnt + 6;
    int* naccp         = cnt + 7;
    float* cs    = (float*)(base + 0);              // wf head (dead after mhead)
    float* cbx   = (float*)(base + 32768);
    int*   cl    = (int*)(base + 131072);
    int*   order = (int*)(base + 163840);
    float* sbox  = (float*)(base + 262144);
    float* sarea = (float*)(base + 344064);
    int*   accbuf = (int*)(base + 368640);
    unsigned long long* keys = (unsigned long long*)A;          // A dead after layer 4
    float* regout            = (float*)(base + 37003264 + 2621440);
    unsigned long long* mask = (unsigned long long*)B;          // B dead after layer 4

    unsigned short* SL_clsL[4] = {wf + (size_t)168 * 73728, wf + (size_t)0 * 73728,
                                  wf + (size_t)16 * 73728,  wf + (size_t)32 * 73728};
    unsigned short* SL_regL[4] = {wf + (size_t)48 * 73728, wf + (size_t)64 * 73728,
                                  wf + (size_t)80 * 73728, wf + (size_t)96 * 73728};
    unsigned short* SL_clsH = wf + (size_t)112 * 73728;
    unsigned short* SL_regH = wf + (size_t)164 * 73728;

    hipMemsetAsync(C, 0, 4 * (size_t)ABUF_B, stream);   // zero C, IN, A, B (contiguous)
    hipMemsetAsync(cnt, 0, 32, stream);

    pad_k<<<(256 * PITCH + 255) / 256, 256, 0, stream>>>(f0, f1, f2, f3, f4, IN);
    wprep_k<<<(184 * 72 * 64 + 255) / 256, 256, 0, stream>>>(ctw, rtw, cow, row_, wf);

    // L1: (IN,IN)->(A,B)    [cls-L1 weights live where C will go]
    conv_t<<<86 * 8, 256, 0, stream>>>(IN, IN, A, B, SL_clsL[0], SL_regL[0], ctb, rtb);
    hipMemsetAsync(C, 0, (size_t)ABUF_B, stream);       // re-zero C (was weight data)
    // L2: (A,B)->(C,IN)
    conv_t<<<86 * 8, 256, 0, stream>>>(A, B, C, IN, SL_clsL[1], SL_regL[1], ctb + 256, rtb + 256);
    // L3: (C,IN)->(A,B)
    conv_t<<<86 * 8, 256, 0, stream>>>(C, IN, A, B, SL_clsL[2], SL_regL[2], ctb + 512, rtb + 512);
    // L4: (A,B)->(C,IN)
    conv_t<<<86 * 8, 256, 0, stream>>>(A, B, C, IN, SL_clsL[3], SL_regL[3], ctb + 768, rtb + 768);

    mhead_t<<<86 * 14, 256, 0, stream>>>(C, IN, SL_clsH, SL_regH, cob, rob, keys, cnt, regout);

    sort5_k<<<5, 1024, 0, stream>>>(keys, cnt);
    emit_k<<<(NCAND + 255) / 256, 256, 0, stream>>>(keys, cnt, regout, anchors, cs, cbx, cl);
    rank_k<<<(NCAND + 255) / 256, 256, 0, stream>>>(cs, cbx, cl, cnt, order, sbox, sarea, nvp);
    mask_k<<<(NCAND * 80 + 255) / 256, 256, 0, stream>>>(sbox, sarea, nvp, mask);
    sweep_k<<<1, 64, 0, stream>>>(mask, nvp, accbuf, naccp);
    fill_k<<<5, 64, 0, stream>>>(cs, cbx, cl, order, accbuf, naccp, out);
}